// Round 1
// baseline (545.356 us; speedup 1.0000x reference)
//
#include <hip/hip_runtime.h>

typedef unsigned short u16;
typedef unsigned int u32;
typedef __attribute__((ext_vector_type(8))) short short8;
typedef __attribute__((ext_vector_type(4))) float f32x4;

#define NF 65536
#define KDIM 1024
#define NDIM 1024
#define NE 8
#define BM 128
#define BN 128
#define MAX_MT (NF / BM + NE)   // 520 upper bound on total m-tiles
#define GEMM_GRID (MAX_MT * 8)  // 4160, divisible by 8 (XCD swizzle valid)

__device__ __forceinline__ u16 f2bf(float f) {
  u32 u = __float_as_uint(f);
  u += 0x7FFF + ((u >> 16) & 1);  // RNE (no NaN in this data)
  return (u16)(u >> 16);
}

// 16B-slot XOR swizzle; designed so both frag reads (rows 0..15 per 16-lane
// group) and staging writes (row strides 16/32) land conflict-free.
__device__ __forceinline__ int swz_slot(int r) {
  return (((r & 7) ^ ((r >> 3) & 7)) << 4);
}

__global__ void k_init(int* counts) {
  int t = threadIdx.x;
  if (t < NE) counts[t] = 0;
}

__global__ void k_hist(const int* __restrict__ ids, int* __restrict__ counts) {
  __shared__ int h[NE];
  int t = threadIdx.x;
  if (t < NE) h[t] = 0;
  __syncthreads();
  int i = blockIdx.x * blockDim.x + t;
  int stride = gridDim.x * blockDim.x;
  for (; i < NF; i += stride) atomicAdd(&h[ids[i]], 1);
  __syncthreads();
  if (t < NE) atomicAdd(&counts[t], h[t]);
}

__global__ void k_scan(const int* __restrict__ counts, int* offsets,
                       int* cursors, int* tile_base) {
  int tot = 0, tb = 0;
  tile_base[0] = 0;
  for (int e = 0; e < NE; ++e) {
    offsets[e] = tot;
    cursors[e] = tot;
    tot += counts[e];
    tb += (counts[e] + BM - 1) / BM;
    tile_base[e + 1] = tb;
  }
}

__global__ void k_scatter(const int* __restrict__ ids, int* __restrict__ cursors,
                          int* __restrict__ perm) {
  int t = blockIdx.x * blockDim.x + threadIdx.x;
  int lane = threadIdx.x & 63;
  int stride = gridDim.x * blockDim.x;
  // NF divisible by total threads -> all waves fully active in __ballot
  for (int i = t; i < NF; i += stride) {
    int e = ids[i];
#pragma unroll
    for (int ee = 0; ee < NE; ++ee) {
      unsigned long long mask = __ballot(e == ee);
      if (mask) {
        int leader = __builtin_ctzll(mask);
        int base = 0;
        if (lane == leader) base = atomicAdd(&cursors[ee], (int)__popcll(mask));
        base = __shfl(base, leader, 64);
        if (e == ee) {
          int rank = (int)__popcll(mask & ((1ull << lane) - 1ull));
          perm[base + rank] = i;
        }
      }
    }
  }
}

// W[e][k][n] fp32  ->  Wt[e][n][k] bf16 (transpose via LDS tile)
__global__ void k_wconv(const float* __restrict__ W, u16* __restrict__ Wt) {
  int b = blockIdx.x;
  int e = b >> 8, rem = b & 255;
  int k0 = (rem >> 4) << 6, n0 = (rem & 15) << 6;
  __shared__ float t[64][65];
  int tid = threadIdx.x;
  int col = tid & 63, rowg = tid >> 6;
  const float* Wp = W + ((size_t)e << 20);
#pragma unroll
  for (int i = 0; i < 16; ++i) {
    int r = rowg + (i << 2);
    t[r][col] = Wp[(size_t)(k0 + r) * 1024 + n0 + col];
  }
  __syncthreads();
  int nrow = tid >> 2, kc = (tid & 3) << 4;
  u32 p[8];
#pragma unroll
  for (int j = 0; j < 8; ++j) {
    u32 lo = f2bf(t[kc + 2 * j][nrow]);
    u32 hi = f2bf(t[kc + 2 * j + 1][nrow]);
    p[j] = lo | (hi << 16);
  }
  u16* dst = Wt + ((size_t)e << 20) + (size_t)(n0 + nrow) * 1024 + k0 + kc;
  *(uint4*)dst = make_uint4(p[0], p[1], p[2], p[3]);
  *((uint4*)dst + 1) = make_uint4(p[4], p[5], p[6], p[7]);
}

// Grouped GEMM: 128x128 tile, BK=64, 4 waves (2x2), 16x16x32 bf16 MFMA.
// A rows gathered via perm; C rows scattered via perm; bias fused.
template <bool USEWT>
__global__ __launch_bounds__(256, 3) void k_gemm(
    const float* __restrict__ A, const float* __restrict__ W,
    const u16* __restrict__ Wt, const float* __restrict__ bias,
    const int* __restrict__ perm, const int* __restrict__ offsets,
    const int* __restrict__ counts, const int* __restrict__ tile_base,
    float* __restrict__ out) {
  int bid = blockIdx.x;
  const int cpx = GEMM_GRID >> 3;
  int l = (bid & 7) * cpx + (bid >> 3);  // XCD swizzle: contiguous logical per XCD
  int mt = l >> 3, nt = l & 7;           // n-tile fastest for A-panel L2 reuse
  if (mt >= tile_base[NE]) return;
  int e = 0;
#pragma unroll
  for (int ee = 0; ee < NE - 1; ++ee)
    if (mt >= tile_base[ee + 1]) e = ee + 1;
  int mloc = mt - tile_base[e];
  int row_base = offsets[e] + (mloc << 7);
  int rim = counts[e] - (mloc << 7);
  rim = rim < BM ? rim : BM;
  int n0 = nt << 7;

  __shared__ u16 Al[BM * 64];
  __shared__ u16 Bl[BN * 64];
  char* alb = (char*)Al;
  char* blb = (char*)Bl;

  int tid = threadIdx.x;
  int lane = tid & 63, wid = tid >> 6;
  int wr = wid >> 1, wc = wid & 1;
  int l15 = lane & 15;
  int lk2 = (lane >> 4) << 4;  // byte offset of this lane's k-octet

  // ---- A staging setup: 16 float4-cols x 16 row-groups, 8 rows/thread
  int acol4 = tid & 15, argp = tid >> 4;
  const float* arow_p[8];
  int aswz[8];
#pragma unroll
  for (int i = 0; i < 8; ++i) {
    int r = argp + (i << 4);
    int rr = r < rim ? r : rim - 1;
    int grow = perm[row_base + rr];
    arow_p[i] = A + (size_t)grow * KDIM + (acol4 << 2);
    aswz[i] = r * 128 + ((acol4 << 3) ^ swz_slot(r));
  }

  // ---- B staging setup
  int bswz[4];
  const u16* brow_wt[4];
  const float* bcol_f = nullptr;
  int bkh = 0;
  if (USEWT) {
    int bcol8 = tid & 7, brgp = tid >> 3;
    const u16* We = Wt + ((size_t)e << 20);
#pragma unroll
    for (int i = 0; i < 4; ++i) {
      int r = brgp + (i << 5);
      bswz[i] = r * 128 + ((bcol8 << 4) ^ swz_slot(r));
      brow_wt[i] = We + (size_t)(n0 + r) * KDIM + (bcol8 << 3);
    }
  } else {
    int bnloc = tid & 127;
    bkh = tid >> 7;
    bcol_f = W + ((size_t)e << 20) + n0 + bnloc;
#pragma unroll
    for (int j = 0; j < 4; ++j)
      bswz[j] = bnloc * 128 + (((bkh << 6) + (j << 4)) ^ swz_slot(bnloc));
  }

  // ---- fragment read byte addresses (kk=0); kk=32 is addr ^ 64
  int ar_addr[4], br_addr[4];
#pragma unroll
  for (int m = 0; m < 4; ++m) {
    int r = (wr << 6) + (m << 4) + l15;
    ar_addr[m] = r * 128 + (lk2 ^ swz_slot(r));
  }
#pragma unroll
  for (int n = 0; n < 4; ++n) {
    int r = (wc << 6) + (n << 4) + l15;
    br_addr[n] = r * 128 + (lk2 ^ swz_slot(r));
  }

  f32x4 acc[4][4];
#pragma unroll
  for (int m = 0; m < 4; ++m)
#pragma unroll
    for (int n = 0; n < 4; ++n) acc[m][n] = f32x4{0.f, 0.f, 0.f, 0.f};

#pragma unroll 1
  for (int kt = 0; kt < KDIM / 64; ++kt) {
    int k0 = kt << 6;
    __syncthreads();
    // stage A (fp32 -> bf16)
#pragma unroll
    for (int i = 0; i < 8; ++i) {
      float4 v = *(const float4*)(arow_p[i] + k0);
      u32 lo = (u32)f2bf(v.x) | ((u32)f2bf(v.y) << 16);
      u32 hi = (u32)f2bf(v.z) | ((u32)f2bf(v.w) << 16);
      *(uint2*)(alb + aswz[i]) = make_uint2(lo, hi);
    }
    // stage B
    if (USEWT) {
#pragma unroll
      for (int i = 0; i < 4; ++i) {
        uint4 v = *(const uint4*)(brow_wt[i] + k0);
        *(uint4*)(blb + bswz[i]) = v;
      }
    } else {
      float vv[32];
#pragma unroll
      for (int i = 0; i < 32; ++i)
        vv[i] = bcol_f[(size_t)(k0 + (bkh << 5) + i) << 10];
#pragma unroll
      for (int j = 0; j < 4; ++j) {
        uint4 pkt;
        pkt.x = (u32)f2bf(vv[j * 8 + 0]) | ((u32)f2bf(vv[j * 8 + 1]) << 16);
        pkt.y = (u32)f2bf(vv[j * 8 + 2]) | ((u32)f2bf(vv[j * 8 + 3]) << 16);
        pkt.z = (u32)f2bf(vv[j * 8 + 4]) | ((u32)f2bf(vv[j * 8 + 5]) << 16);
        pkt.w = (u32)f2bf(vv[j * 8 + 6]) | ((u32)f2bf(vv[j * 8 + 7]) << 16);
        *(uint4*)(blb + bswz[j]) = pkt;
      }
    }
    __syncthreads();
    // compute: 16 ds_read_b128 + 32 MFMA per K-step
#pragma unroll
    for (int kk = 0; kk < 2; ++kk) {
      int kx = kk << 6;
      short8 af[4], bfr[4];
#pragma unroll
      for (int m = 0; m < 4; ++m)
        af[m] = __builtin_bit_cast(short8, *(const uint4*)(alb + (ar_addr[m] ^ kx)));
#pragma unroll
      for (int n = 0; n < 4; ++n)
        bfr[n] = __builtin_bit_cast(short8, *(const uint4*)(blb + (br_addr[n] ^ kx)));
#pragma unroll
      for (int m = 0; m < 4; ++m)
#pragma unroll
        for (int n = 0; n < 4; ++n)
          acc[m][n] = __builtin_amdgcn_mfma_f32_16x16x32_bf16(af[m], bfr[n],
                                                              acc[m][n], 0, 0, 0);
    }
  }

  // epilogue: C row = (lane>>4)*4 + reg, col = lane&15 (m89-verified layout)
  float bv[4];
#pragma unroll
  for (int n = 0; n < 4; ++n)
    bv[n] = bias[(e << 10) + n0 + (wc << 6) + (n << 4) + l15];
  int rq = (lane >> 4) << 2;
#pragma unroll
  for (int m = 0; m < 4; ++m) {
#pragma unroll
    for (int j = 0; j < 4; ++j) {
      int rl = (wr << 6) + (m << 4) + rq + j;
      if (rl < rim) {
        int grow = perm[row_base + rl];
        float* orow = out + (size_t)grow * NDIM + n0 + (wc << 6) + l15;
#pragma unroll
        for (int n = 0; n < 4; ++n) orow[n << 4] = acc[m][n][j] + bv[n];
      }
    }
  }
}

extern "C" void kernel_launch(void* const* d_in, const int* in_sizes, int n_in,
                              void* d_out, int out_size, void* d_ws,
                              size_t ws_size, hipStream_t stream) {
  const float* A = (const float*)d_in[0];
  const int* ids = (const int*)d_in[1];
  const float* W = (const float*)d_in[2];
  const float* bias = (const float*)d_in[3];
  float* out = (float*)d_out;

  char* ws = (char*)d_ws;
  int* counts = (int*)ws;          // 8
  int* offsets = counts + 8;       // 8
  int* cursors = offsets + 8;      // 8
  int* tile_base = cursors + 8;    // 9
  int* perm = (int*)(ws + 256);    // 65536 ints
  u16* Wt = (u16*)(ws + 256 + (size_t)NF * 4);  // 16 MB bf16, 16B-aligned
  size_t need_wt = 256 + (size_t)NF * 4 + (size_t)NE * KDIM * NDIM * 2;
  bool useWt = ws_size >= need_wt;

  k_init<<<1, 64, 0, stream>>>(counts);
  k_hist<<<64, 256, 0, stream>>>(ids, counts);
  k_scan<<<1, 1, 0, stream>>>(counts, offsets, cursors, tile_base);
  k_scatter<<<64, 256, 0, stream>>>(ids, cursors, perm);
  if (useWt) {
    k_wconv<<<NE * 256, 256, 0, stream>>>(W, Wt);
    k_gemm<true><<<GEMM_GRID, 256, 0, stream>>>(A, W, Wt, bias, perm, offsets,
                                                counts, tile_base, out);
  } else {
    k_gemm<false><<<GEMM_GRID, 256, 0, stream>>>(A, W, Wt, bias, perm, offsets,
                                                 counts, tile_base, out);
  }
}

// Round 3
// 306.886 us; speedup vs baseline: 1.7771x; 1.7771x over previous
//
#include <hip/hip_runtime.h>

typedef unsigned short u16;
typedef unsigned int u32;
typedef __attribute__((ext_vector_type(8))) short short8;
typedef __attribute__((ext_vector_type(4))) float f32x4;

#define NF 65536
#define KDIM 1024
#define NDIM 1024
#define NE 8
#define BM 128
#define BN 128
#define MAX_MT (NF / BM + NE)   // 520 upper bound on total m-tiles
#define GEMM_GRID (MAX_MT * 8)  // 4160, divisible by 8 (XCD swizzle valid)
#define TILE_B 16384            // one 128x64 bf16 tile = LDS image bytes
#define SORT_BLOCKS 64

#define AS1 __attribute__((address_space(1)))
#define AS3 __attribute__((address_space(3)))

__device__ __forceinline__ u16 f2bf(float f) {
  u32 u = __float_as_uint(f);
  u += 0x7FFF + ((u >> 16) & 1);  // RNE (no NaN in this data)
  return (u16)(u >> 16);
}

// 3-bit slot swizzle within a 128B row (8 x 16B slots)
__device__ __forceinline__ int swz8(int r) {
  return (r & 7) ^ ((r >> 3) & 7);
}
__device__ __forceinline__ int swz_slot(int r) { return swz8(r) << 4; }

__device__ __forceinline__ void cp16(void* l, const void* g) {
  __builtin_amdgcn_global_load_lds((const AS1 unsigned int*)g,
                                   (AS3 unsigned int*)l, 16, 0, 0);
}

// ---------- deterministic (atomic-free) counting sort ----------
// Block b owns indices [b*1024,(b+1)*1024), processed as 16 fixed (s,wave)
// groups of 64 contiguous indices. All ranks derived from ballots -> perm is
// a pure function of ids (bit-identical every call).
__global__ void k_cnt(const int* __restrict__ ids, int* __restrict__ gcnt) {
  __shared__ int wc[16][NE];
  int b = blockIdx.x, t = threadIdx.x;
  int w = t >> 6, lane = t & 63;
  if (t < 16 * NE) ((int*)wc)[t] = 0;
  __syncthreads();
  for (int s = 0; s < 4; ++s) {
    int i = (b << 10) + (s << 8) + t;
    int e = ids[i];
#pragma unroll
    for (int ee = 0; ee < NE; ++ee) {
      unsigned long long mask = __ballot(e == ee);
      if (lane == 0) wc[(s << 2) + w][ee] = (int)__popcll(mask);
    }
  }
  __syncthreads();
  if (t < NE) {
    int sum = 0;
#pragma unroll
    for (int j = 0; j < 16; ++j) sum += wc[j][t];
    gcnt[b * NE + t] = sum;
  }
}

__global__ void k_excl(const int* __restrict__ gcnt, int* __restrict__ counts,
                       int* __restrict__ offsets, int* __restrict__ tile_base,
                       int* __restrict__ base) {
  __shared__ int tot[NE], offs[NE];
  int t = threadIdx.x;
  if (t < NE) {
    int s = 0;
    for (int b = 0; b < SORT_BLOCKS; ++b) s += gcnt[b * NE + t];
    tot[t] = s;
    counts[t] = s;
  }
  __syncthreads();
  if (t == 0) {
    int run = 0, tb = 0;
    tile_base[0] = 0;
    for (int e = 0; e < NE; ++e) {
      offsets[e] = run;
      offs[e] = run;
      run += tot[e];
      tb += (tot[e] + BM - 1) / BM;
      tile_base[e + 1] = tb;
    }
  }
  __syncthreads();
  if (t < NE) {
    int run = offs[t];
    for (int b = 0; b < SORT_BLOCKS; ++b) {
      base[b * NE + t] = run;
      run += gcnt[b * NE + t];
    }
  }
}

__global__ void k_place(const int* __restrict__ ids, const int* __restrict__ base,
                        int* __restrict__ perm) {
  __shared__ int wc[16][NE], wsc[16][NE];
  int b = blockIdx.x, t = threadIdx.x;
  int w = t >> 6, lane = t & 63;
  for (int s = 0; s < 4; ++s) {
    int i = (b << 10) + (s << 8) + t;
    int e = ids[i];
#pragma unroll
    for (int ee = 0; ee < NE; ++ee) {
      unsigned long long mask = __ballot(e == ee);
      if (lane == 0) wc[(s << 2) + w][ee] = (int)__popcll(mask);
    }
  }
  __syncthreads();
  if (t < NE) {
    int run = 0;
#pragma unroll
    for (int j = 0; j < 16; ++j) {
      wsc[j][t] = run;
      run += wc[j][t];
    }
  }
  __syncthreads();
  for (int s = 0; s < 4; ++s) {
    int i = (b << 10) + (s << 8) + t;
    int e = ids[i];
#pragma unroll
    for (int ee = 0; ee < NE; ++ee) {
      unsigned long long mask = __ballot(e == ee);
      if (e == ee) {
        int rank = (int)__popcll(mask & ((1ull << lane) - 1ull));
        perm[base[b * NE + e] + wsc[(s << 2) + w][e] + rank] = i;
      }
    }
  }
}

// ---------- operand pre-formatting ----------
// Gather+convert A into per-(mt,kt) 16KB tiles laid out as the swizzled LDS
// image: byte o of tile -> row r=o>>7, slot s=((o>>4)&7)^swz8(r), k=s*8.
__global__ void k_aconv(const float* __restrict__ A, const int* __restrict__ perm,
                        const int* __restrict__ counts,
                        const int* __restrict__ offsets,
                        const int* __restrict__ tile_base, u16* __restrict__ Abf) {
  int b = blockIdx.x;  // MAX_MT*16
  int mt = b >> 4, kt = b & 15;
  if (mt >= tile_base[NE]) return;
  int e = 0;
#pragma unroll
  for (int ee = 0; ee < NE - 1; ++ee)
    if (mt >= tile_base[ee + 1]) e = ee + 1;
  int mloc = mt - tile_base[e];
  int row_base = offsets[e] + (mloc << 7);
  int rim = counts[e] - (mloc << 7);
  rim = rim < BM ? rim : BM;
  int tid = threadIdx.x;
  char* dst = (char*)Abf + (size_t)b * TILE_B;  // b == mt*16+kt
#pragma unroll
  for (int i = 0; i < 4; ++i) {
    int o = (i << 12) + (tid << 4);
    int r = o >> 7;
    int s = ((o >> 4) & 7) ^ swz8(r);
    uint4 pkt = make_uint4(0, 0, 0, 0);
    if (r < rim) {
      int g = perm[row_base + r];
      const float* src = A + (size_t)g * KDIM + (kt << 6) + (s << 3);
      float4 v0 = ((const float4*)src)[0];
      float4 v1 = ((const float4*)src)[1];
      pkt.x = (u32)f2bf(v0.x) | ((u32)f2bf(v0.y) << 16);
      pkt.y = (u32)f2bf(v0.z) | ((u32)f2bf(v0.w) << 16);
      pkt.z = (u32)f2bf(v1.x) | ((u32)f2bf(v1.y) << 16);
      pkt.w = (u32)f2bf(v1.z) | ((u32)f2bf(v1.w) << 16);
    }
    *(uint4*)(dst + o) = pkt;
  }
}

// W[e][k][n] fp32 -> bf16 tiles [e][nt][kt][swizzled 128x64 image]
__global__ void k_wconv2(const float* __restrict__ W, u16* __restrict__ Wt) {
  int b = blockIdx.x;  // 8*8*16 = 1024 : b = (e*8+nt)*16+kt
  int e = b >> 7, nt = (b >> 4) & 7, kt = b & 15;
  int tid = threadIdx.x;
  const float* We = W + ((size_t)e << 20);
  char* dst = (char*)Wt + (size_t)b * TILE_B;
#pragma unroll
  for (int i = 0; i < 4; ++i) {
    int o = (i << 12) + (tid << 4);
    int r = o >> 7;
    int s = ((o >> 4) & 7) ^ swz8(r);
    int n = (nt << 7) + r;
    int k = (kt << 6) + (s << 3);
    u32 p[4];
#pragma unroll
    for (int j = 0; j < 4; ++j) {
      u32 lo = f2bf(We[(size_t)(k + 2 * j) * NDIM + n]);
      u32 hi = f2bf(We[(size_t)(k + 2 * j + 1) * NDIM + n]);
      p[j] = lo | (hi << 16);
    }
    *(uint4*)(dst + o) = make_uint4(p[0], p[1], p[2], p[3]);
  }
}

// ---------- m97-structure grouped GEMM ----------
__global__ __launch_bounds__(256, 4) void k_gemm_fast(
    const u16* __restrict__ Abf, const u16* __restrict__ Wt,
    const float* __restrict__ bias, const int* __restrict__ perm,
    const int* __restrict__ offsets, const int* __restrict__ counts,
    const int* __restrict__ tile_base, float* __restrict__ out) {
  int bid = blockIdx.x;
  const int cpx = GEMM_GRID >> 3;
  int l = (bid & 7) * cpx + (bid >> 3);  // XCD swizzle
  int mt = l >> 3, nt = l & 7;           // n fastest: A-panel L2 reuse
  if (mt >= tile_base[NE]) return;
  int e = 0;
#pragma unroll
  for (int ee = 0; ee < NE - 1; ++ee)
    if (mt >= tile_base[ee + 1]) e = ee + 1;
  int mloc = mt - tile_base[e];
  int row_base = offsets[e] + (mloc << 7);
  int rim = counts[e] - (mloc << 7);
  rim = rim < BM ? rim : BM;
  int n0 = nt << 7;

  __shared__ __align__(16) char lds[2 * TILE_B];
  char* la = lds;
  char* lb = lds + TILE_B;

  int tid = threadIdx.x;
  int lane = tid & 63, wid = tid >> 6;
  int wr = wid >> 1, wc = wid & 1;
  int l15 = lane & 15;
  int lk2 = (lane >> 4) << 4;

  const char* srcA = (const char*)Abf + (size_t)(mt << 4) * TILE_B;
  const char* srcB = (const char*)Wt + (size_t)(((e << 3) + nt) << 4) * TILE_B;

  int ar_addr[4], br_addr[4];
#pragma unroll
  for (int m = 0; m < 4; ++m) {
    int r = (wr << 6) + (m << 4) + l15;
    ar_addr[m] = r * 128 + (lk2 ^ swz_slot(r));
  }
#pragma unroll
  for (int n = 0; n < 4; ++n) {
    int r = (wc << 6) + (n << 4) + l15;
    br_addr[n] = r * 128 + (lk2 ^ swz_slot(r));
  }

  f32x4 acc[4][4];
#pragma unroll
  for (int m = 0; m < 4; ++m)
#pragma unroll
    for (int n = 0; n < 4; ++n) acc[m][n] = f32x4{0.f, 0.f, 0.f, 0.f};

  int toff = tid << 4;
#pragma unroll 1
  for (int kt = 0; kt < KDIM / 64; ++kt) {
    __syncthreads();  // previous compute done; LDS reusable
    const char* ga = srcA + kt * TILE_B;
    const char* gb = srcB + kt * TILE_B;
#pragma unroll
    for (int j = 0; j < 4; ++j) cp16(la + toff + (j << 12), ga + toff + (j << 12));
#pragma unroll
    for (int j = 0; j < 4; ++j) cp16(lb + toff + (j << 12), gb + toff + (j << 12));
    // explicit drain of the async loads (belt + suspenders vs compiler fence)
    asm volatile("s_waitcnt vmcnt(0)" ::: "memory");
    __builtin_amdgcn_sched_barrier(0);
    __syncthreads();
#pragma unroll
    for (int kk = 0; kk < 2; ++kk) {
      int kx = kk << 6;
      short8 af[4], bfr[4];
#pragma unroll
      for (int m = 0; m < 4; ++m)
        af[m] = __builtin_bit_cast(short8, *(const uint4*)(la + (ar_addr[m] ^ kx)));
#pragma unroll
      for (int n = 0; n < 4; ++n)
        bfr[n] = __builtin_bit_cast(short8, *(const uint4*)(lb + (br_addr[n] ^ kx)));
#pragma unroll
      for (int m = 0; m < 4; ++m)
#pragma unroll
        for (int n = 0; n < 4; ++n)
          acc[m][n] = __builtin_amdgcn_mfma_f32_16x16x32_bf16(af[m], bfr[n],
                                                              acc[m][n], 0, 0, 0);
    }
  }

  // epilogue: C row = (lane>>4)*4 + reg, col = lane&15 (m89 layout)
  float bv[4];
#pragma unroll
  for (int n = 0; n < 4; ++n)
    bv[n] = bias[(e << 10) + n0 + (wc << 6) + (n << 4) + l15];
  int rq = (lane >> 4) << 2;
#pragma unroll
  for (int m = 0; m < 4; ++m) {
#pragma unroll
    for (int j = 0; j < 4; ++j) {
      int rl = (wr << 6) + (m << 4) + rq + j;
      if (rl < rim) {
        int grow = perm[row_base + rl];
        float* orow = out + (size_t)grow * NDIM + n0 + (wc << 6) + l15;
#pragma unroll
        for (int n = 0; n < 4; ++n) orow[n << 4] = acc[m][n][j] + bv[n];
      }
    }
  }
}

// ---------------- fallback (reg-staging, strided fp32 B) ----------------
__global__ __launch_bounds__(256, 3) void k_gemm_slow(
    const float* __restrict__ A, const float* __restrict__ W,
    const float* __restrict__ bias, const int* __restrict__ perm,
    const int* __restrict__ offsets, const int* __restrict__ counts,
    const int* __restrict__ tile_base, float* __restrict__ out) {
  int bid = blockIdx.x;
  const int cpx = GEMM_GRID >> 3;
  int l = (bid & 7) * cpx + (bid >> 3);
  int mt = l >> 3, nt = l & 7;
  if (mt >= tile_base[NE]) return;
  int e = 0;
#pragma unroll
  for (int ee = 0; ee < NE - 1; ++ee)
    if (mt >= tile_base[ee + 1]) e = ee + 1;
  int mloc = mt - tile_base[e];
  int row_base = offsets[e] + (mloc << 7);
  int rim = counts[e] - (mloc << 7);
  rim = rim < BM ? rim : BM;
  int n0 = nt << 7;

  __shared__ u16 Al[BM * 64];
  __shared__ u16 Bl[BN * 64];
  char* alb = (char*)Al;
  char* blb = (char*)Bl;

  int tid = threadIdx.x;
  int lane = tid & 63, wid = tid >> 6;
  int wr = wid >> 1, wc = wid & 1;
  int l15 = lane & 15;
  int lk2 = (lane >> 4) << 4;

  int acol4 = tid & 15, argp = tid >> 4;
  const float* arow_p[8];
  int aswz[8];
#pragma unroll
  for (int i = 0; i < 8; ++i) {
    int r = argp + (i << 4);
    int rr = r < rim ? r : rim - 1;
    int grow = perm[row_base + rr];
    arow_p[i] = A + (size_t)grow * KDIM + (acol4 << 2);
    aswz[i] = r * 128 + ((acol4 << 3) ^ swz_slot(r));
  }
  int bnloc = tid & 127;
  int bkh = tid >> 7;
  const float* bcol_f = W + ((size_t)e << 20) + n0 + bnloc;
  int bswz[4];
#pragma unroll
  for (int j = 0; j < 4; ++j)
    bswz[j] = bnloc * 128 + (((bkh << 6) + (j << 4)) ^ swz_slot(bnloc));

  int ar_addr[4], br_addr[4];
#pragma unroll
  for (int m = 0; m < 4; ++m) {
    int r = (wr << 6) + (m << 4) + l15;
    ar_addr[m] = r * 128 + (lk2 ^ swz_slot(r));
  }
#pragma unroll
  for (int n = 0; n < 4; ++n) {
    int r = (wc << 6) + (n << 4) + l15;
    br_addr[n] = r * 128 + (lk2 ^ swz_slot(r));
  }

  f32x4 acc[4][4];
#pragma unroll
  for (int m = 0; m < 4; ++m)
#pragma unroll
    for (int n = 0; n < 4; ++n) acc[m][n] = f32x4{0.f, 0.f, 0.f, 0.f};

#pragma unroll 1
  for (int kt = 0; kt < KDIM / 64; ++kt) {
    int k0 = kt << 6;
    __syncthreads();
#pragma unroll
    for (int i = 0; i < 8; ++i) {
      float4 v = *(const float4*)(arow_p[i] + k0);
      u32 lo = (u32)f2bf(v.x) | ((u32)f2bf(v.y) << 16);
      u32 hi = (u32)f2bf(v.z) | ((u32)f2bf(v.w) << 16);
      *(uint2*)(alb + aswz[i]) = make_uint2(lo, hi);
    }
    float vv[32];
#pragma unroll
    for (int i = 0; i < 32; ++i)
      vv[i] = bcol_f[(size_t)(k0 + (bkh << 5) + i) << 10];
#pragma unroll
    for (int j = 0; j < 4; ++j) {
      uint4 pkt;
      pkt.x = (u32)f2bf(vv[j * 8 + 0]) | ((u32)f2bf(vv[j * 8 + 1]) << 16);
      pkt.y = (u32)f2bf(vv[j * 8 + 2]) | ((u32)f2bf(vv[j * 8 + 3]) << 16);
      pkt.z = (u32)f2bf(vv[j * 8 + 4]) | ((u32)f2bf(vv[j * 8 + 5]) << 16);
      pkt.w = (u32)f2bf(vv[j * 8 + 6]) | ((u32)f2bf(vv[j * 8 + 7]) << 16);
      *(uint4*)(blb + bswz[j]) = pkt;
    }
    __syncthreads();
#pragma unroll
    for (int kk = 0; kk < 2; ++kk) {
      int kx = kk << 6;
      short8 af[4], bfr[4];
#pragma unroll
      for (int m = 0; m < 4; ++m)
        af[m] = __builtin_bit_cast(short8, *(const uint4*)(alb + (ar_addr[m] ^ kx)));
#pragma unroll
      for (int n = 0; n < 4; ++n)
        bfr[n] = __builtin_bit_cast(short8, *(const uint4*)(blb + (br_addr[n] ^ kx)));
#pragma unroll
      for (int m = 0; m < 4; ++m)
#pragma unroll
        for (int n = 0; n < 4; ++n)
          acc[m][n] = __builtin_amdgcn_mfma_f32_16x16x32_bf16(af[m], bfr[n],
                                                              acc[m][n], 0, 0, 0);
    }
  }

  float bv[4];
#pragma unroll
  for (int n = 0; n < 4; ++n)
    bv[n] = bias[(e << 10) + n0 + (wc << 6) + (n << 4) + l15];
  int rq = (lane >> 4) << 2;
#pragma unroll
  for (int m = 0; m < 4; ++m) {
#pragma unroll
    for (int j = 0; j < 4; ++j) {
      int rl = (wr << 6) + (m << 4) + rq + j;
      if (rl < rim) {
        int grow = perm[row_base + rl];
        float* orow = out + (size_t)grow * NDIM + n0 + (wc << 6) + l15;
#pragma unroll
        for (int n = 0; n < 4; ++n) orow[n << 4] = acc[m][n][j] + bv[n];
      }
    }
  }
}

extern "C" void kernel_launch(void* const* d_in, const int* in_sizes, int n_in,
                              void* d_out, int out_size, void* d_ws,
                              size_t ws_size, hipStream_t stream) {
  const float* A = (const float*)d_in[0];
  const int* ids = (const int*)d_in[1];
  const float* W = (const float*)d_in[2];
  const float* bias = (const float*)d_in[3];
  float* out = (float*)d_out;

  char* ws = (char*)d_ws;
  int* counts = (int*)ws;            // ws+0    : 8
  int* offsets = (int*)(ws + 32);    // ws+32   : 8
  int* tile_base = (int*)(ws + 64);  // ws+64   : 9
  int* gcnt = (int*)(ws + 128);      // ws+128  : 512
  int* base = (int*)(ws + 2176);     // ws+2176 : 512
  int* perm = (int*)(ws + 8192);     // ws+8192 : 65536 ints
  const size_t abf_off = 524288;
  const size_t abf_sz = (size_t)MAX_MT * 16 * TILE_B;  // 136,314,880
  const size_t wt_off = abf_off + abf_sz;
  const size_t wt_sz = (size_t)NE * 8 * 16 * TILE_B;  // 16,777,216
  u16* Abf = (u16*)(ws + abf_off);
  u16* Wt = (u16*)(ws + wt_off);
  bool fast = ws_size >= wt_off + wt_sz;

  k_cnt<<<SORT_BLOCKS, 256, 0, stream>>>(ids, gcnt);
  k_excl<<<1, 64, 0, stream>>>(gcnt, counts, offsets, tile_base, base);
  k_place<<<SORT_BLOCKS, 256, 0, stream>>>(ids, base, perm);
  if (fast) {
    k_wconv2<<<NE * 8 * 16, 256, 0, stream>>>(W, Wt);
    k_aconv<<<MAX_MT * 16, 256, 0, stream>>>(A, perm, counts, offsets,
                                             tile_base, Abf);
    k_gemm_fast<<<GEMM_GRID, 256, 0, stream>>>(Abf, Wt, bias, perm, offsets,
                                               counts, tile_base, out);
  } else {
    k_gemm_slow<<<GEMM_GRID, 256, 0, stream>>>(A, W, bias, perm, offsets,
                                               counts, tile_base, out);
  }
}